// Round 3
// baseline (444.147 us; speedup 1.0000x reference)
//
#include <hip/hip_runtime.h>
#include <stdint.h>

#define NCLS  21
#define CDIM  256
#define HWSZ  16384
#define NPIX  131072
#define EPSV  1e-6f
#define NEGV  -1e30f
#define CAP_W 4096
#define CAP_S 16384
#define KSEL  256
#define NPART 8            // strong top-k partitions per class
#define P2M   512          // pixels per k1a block
#define NBLKM (NPIX/P2M)   // 256 blocks
#define CPAD  (CDIM+1)

__device__ __forceinline__ uint64_t pack_key(float v, unsigned idx) {
  unsigned u = __float_as_uint(v);
  u = (u & 0x80000000u) ? ~u : (u | 0x80000000u);  // order-preserving map
  return ((uint64_t)(~u) << 32) | (uint64_t)idx;   // ascending key == descending value, tie -> low idx
}

// ---------------- K0: normalize prototypes, zero wsum + global counters ----------------
__global__ void k0_init(const float* __restrict__ mb, float* pn, float* wsum,
                        int* wcnt, int* scnt) {
  int k = blockIdx.x, t = threadIdx.x;
  float v = mb[k * CDIM + t];
  float s = v * v;
  for (int o = 32; o > 0; o >>= 1) s += __shfl_down(s, o, 64);
  __shared__ float wsh[4];
  int wid = t >> 6, lane = t & 63;
  if (lane == 0) wsh[wid] = s;
  __syncthreads();
  float tot = wsh[0] + wsh[1] + wsh[2] + wsh[3];
  float inv = 1.0f / fmaxf(sqrtf(tot), EPSV);
  pn[k * CDIM + t] = v * inv;
  wsum[k * CDIM + t] = 0.0f;
  if (k == 0 && t < 2 * NCLS) {
    if (t < NCLS) wcnt[t] = 0; else scnt[t - NCLS] = 0;
  }
}

// ---------------- K1a-mega: stream fw/fs (NT loads), full sims, keys, wsum, counts ----------------
// grid: NBLKM=256 blocks x 256 threads. Block owns 512 pixels x all 256 channels.
// Thread owns 2 pixels. Key lists allocated via per-block LDS count + one global
// atomicAdd range reservation per class (list order nondeterministic; selection
// deterministic because pack_key embeds the pixel index).
__global__ __launch_bounds__(256)
void k1a_mega(const float* __restrict__ fw, const float* __restrict__ fs,
              const float* __restrict__ prob, const int* __restrict__ seg,
              const int* __restrict__ ign, const float* __restrict__ pn,
              float* wsum, int* wcnt, int* scnt,
              uint64_t* wkeys, uint64_t* skeys) {
  __shared__ float pnT[CDIM * NCLS];      // [c][k]  21.5 KB
  __shared__ float wloc[NCLS * CPAD];     // [k][c] padded  21.6 KB
  __shared__ int cw[NCLS], cs[NCLS], bw[NCLS], bs[NCLS];
  int t = threadIdx.x, pg = blockIdx.x;
  for (int i = t; i < CDIM * NCLS; i += 256) {
    int c = i / NCLS, k = i % NCLS;
    pnT[i] = pn[k * CDIM + c];
  }
  for (int i = t; i < NCLS * CPAD; i += 256) wloc[i] = 0.0f;
  if (t < NCLS) { cw[t] = 0; cs[t] = 0; }
  __syncthreads();

  int base = pg * P2M;
  int b = base >> 14;                  // P2M divides HWSZ
  int hw0 = (base & (HWSZ - 1)) + t;
  int n0 = base + t, n1 = base + 256 + t;
  int sg0 = seg[n0], sg1 = seg[n1];
  int ig0 = ign[n0], ig1 = ign[n1];
  float pr0 = prob[n0], pr1 = prob[n1];
  bool va0 = (ig0 != 255), va1 = (ig1 != 255);
  bool cf0 = va0 && (pr0 > 0.95f), cf1 = va1 && (pr1 > 0.95f);

  const float* fwp = fw + (size_t)b * CDIM * HWSZ + hw0;
  const float* fsp = fs + (size_t)b * CDIM * HWSZ + hw0;

  float dw0 = 0, nw0 = 0, ds0 = 0, ns0 = 0;
  float dw1 = 0, nw1 = 0, ds1 = 0, ns1 = 0;
#pragma unroll 8
  for (int c = 0; c < CDIM; ++c) {
    size_t o = (size_t)c * HWSZ;
    float a0 = __builtin_nontemporal_load(fwp + o);
    float a1 = __builtin_nontemporal_load(fwp + o + 256);
    float s0 = __builtin_nontemporal_load(fsp + o);
    float s1 = __builtin_nontemporal_load(fsp + o + 256);
    float p0 = pnT[c * NCLS + sg0];
    float p1 = pnT[c * NCLS + sg1];
    dw0 = fmaf(a0, p0, dw0); nw0 = fmaf(a0, a0, nw0);
    ds0 = fmaf(s0, p0, ds0); ns0 = fmaf(s0, s0, ns0);
    dw1 = fmaf(a1, p1, dw1); nw1 = fmaf(a1, a1, nw1);
    ds1 = fmaf(s1, p1, ds1); ns1 = fmaf(s1, s1, ns1);
    if (cf0) atomicAdd(&wloc[sg0 * CPAD + c], a0);
    if (cf1) atomicAdd(&wloc[sg1 * CPAD + c], a1);
  }

  // local slot allocation
  int ls0 = 0, lw0 = 0, ls1 = 0, lw1 = 0;
  if (va0) ls0 = atomicAdd(&cs[sg0], 1);
  if (va1) ls1 = atomicAdd(&cs[sg1], 1);
  if (cf0) lw0 = atomicAdd(&cw[sg0], 1);
  if (cf1) lw1 = atomicAdd(&cw[sg1], 1);
  __syncthreads();
  if (t < NCLS) {
    bs[t] = atomicAdd(&scnt[t], cs[t]);
    bw[t] = atomicAdd(&wcnt[t], cw[t]);
  }
  __syncthreads();
  if (va0) {
    float sim_s = ds0 / fmaxf(sqrtf(ns0), EPSV);
    int pos = bs[sg0] + ls0;
    if (pos < CAP_S) skeys[(size_t)sg0 * CAP_S + pos] = pack_key(-sim_s, (unsigned)n0);
    if (cf0) {
      float sim_w = dw0 / fmaxf(sqrtf(nw0), EPSV);
      int pw = bw[sg0] + lw0;
      if (pw < CAP_W) wkeys[(size_t)sg0 * CAP_W + pw] = pack_key(sim_w, (unsigned)n0);
    }
  }
  if (va1) {
    float sim_s = ds1 / fmaxf(sqrtf(ns1), EPSV);
    int pos = bs[sg1] + ls1;
    if (pos < CAP_S) skeys[(size_t)sg1 * CAP_S + pos] = pack_key(-sim_s, (unsigned)n1);
    if (cf1) {
      float sim_w = dw1 / fmaxf(sqrtf(nw1), EPSV);
      int pw = bw[sg1] + lw1;
      if (pw < CAP_W) wkeys[(size_t)sg1 * CAP_W + pw] = pack_key(sim_w, (unsigned)n1);
    }
  }
  // wsum flush (wloc complete before the two barriers above)
  for (int i = t; i < NCLS * CDIM; i += 256) {
    int k = i >> 8, c = i & 255;
    float v = wloc[k * CPAD + c];
    if (v != 0.0f) atomicAdd(&wsum[k * CDIM + c], v);
  }
}

// ---------------- top-256 select (cutoff-filtered bitonic), 256 threads ----------------
__device__ void select_topk(const uint64_t* __restrict__ list, int cnt,
                            uint64_t* T, uint64_t* P, int* pcnt, int* woff) {
  int t = threadIdx.x;
  T[t] = ~0ull;
  if (t == 0) *pcnt = 0;
  __syncthreads();
  for (int base = 0; base < cnt; base += 256) {
    uint64_t key = (base + t < cnt) ? list[base + t] : ~0ull;
    uint64_t cutoff = T[KSEL - 1];
    bool pred = key < cutoff;
    unsigned long long mask = __ballot(pred);
    int wid = t >> 6, lane = t & 63;
    if (lane == 0) woff[wid] = __popcll(mask);
    int prefix = __popcll(mask & ((1ull << lane) - 1ull));
    __syncthreads();
    int off = 0;
    for (int w2 = 0; w2 < wid; ++w2) off += woff[w2];
    int total = woff[0] + woff[1] + woff[2] + woff[3];
    int old = *pcnt;
    if (pred) P[old + off + prefix] = key;
    int newc = old + total;
    __syncthreads();
    if (t == 0) *pcnt = newc;
    bool last = (base + 256 >= cnt);
    if (newc >= KSEL || (last && newc > 0)) {
      for (int i2 = t; i2 < 2 * KSEL; i2 += 256)
        if (i2 >= newc) P[i2] = ~0ull;
      for (unsigned size = 2; size <= 2 * KSEL; size <<= 1) {
        for (unsigned stride = size >> 1; stride > 0; stride >>= 1) {
          __syncthreads();
          unsigned lo = stride - 1;
          unsigned i = (((unsigned)t & ~lo) << 1) | ((unsigned)t & lo);
          unsigned j = i | stride;
          uint64_t a = P[i], b = P[j];
          bool up = ((i & size) == 0);
          if ((a > b) == up) { P[i] = b; P[j] = a; }
        }
      }
      __syncthreads();
      uint64_t a = T[t], b = P[KSEL - 1 - t];
      T[t] = a < b ? a : b;
      for (unsigned stride = KSEL / 2; stride > 0; stride >>= 1) {
        __syncthreads();
        if (((unsigned)t & stride) == 0) {
          uint64_t x = T[t], y = T[t + stride];
          if (x > y) { T[t] = y; T[t + stride] = x; }
        }
      }
      __syncthreads();
      if (t == 0) *pcnt = 0;
      __syncthreads();
    } else {
      __syncthreads();
    }
  }
}

// ---------------- K2: weak top-16 (full) + strong top-256 (partitioned) ----------------
__global__ void k2_topk(const uint64_t* __restrict__ wkeys, const uint64_t* __restrict__ skeys,
                        const int* wcnt, const int* scnt,
                        uint64_t* psel, int* idxw) {
  __shared__ uint64_t T[KSEL];
  __shared__ uint64_t P[2 * KSEL];
  __shared__ int pcnt;
  __shared__ int woff[4];
  int bid = blockIdx.x, t = threadIdx.x;
  if (bid < NCLS * NPART) {
    int k = bid / NPART, p = bid % NPART;
    int cnt = min(scnt[k], CAP_S);
    int chunk = (cnt + NPART - 1) / NPART;
    int lo = p * chunk;
    int hi = min(lo + chunk, cnt);
    int c = hi > lo ? hi - lo : 0;
    select_topk(skeys + (size_t)k * CAP_S + lo, c, T, P, &pcnt, woff);
    psel[((size_t)k * NPART + p) * KSEL + t] = T[t];
  } else {
    int k = bid - NCLS * NPART;
    int cnt = min(wcnt[k], CAP_W);
    select_topk(wkeys + (size_t)k * CAP_W, cnt, T, P, &pcnt, woff);
    if (t < 16) idxw[k * 16 + t] = (int)(unsigned)(T[t] & 0xFFFFFFFFull);
  }
}

// ---------------- K2m: merge 8 sorted 256-lists -> top-256 via min-merge + bitonic clean ----------------
__global__ void k2m_merge(const uint64_t* __restrict__ psel, int* idxs) {
  int k = blockIdx.x, t = threadIdx.x;
  __shared__ uint64_t M[NPART * KSEL];   // 2048
  __shared__ uint64_t M2[4 * KSEL];      // 1024
  for (int i = t; i < NPART * KSEL; i += 256) M[i] = psel[(size_t)k * NPART * KSEL + i];
  __syncthreads();
  // round 1: 8 lists -> 4
#pragma unroll
  for (int p = 0; p < 4; ++p) {
    uint64_t a = M[p * 512 + t], b = M[p * 512 + 511 - t];
    M2[p * 256 + t] = a < b ? a : b;
  }
  for (int str = 128; str > 0; str >>= 1) {
    __syncthreads();
    for (int q = t; q < 4 * 128; q += 256) {
      int list = q >> 7, r = q & 127;
      int i = ((r & ~(str - 1)) << 1) | (r & (str - 1));
      int ai = list * 256 + i, bi = ai + str;
      uint64_t x = M2[ai], y = M2[bi];
      if (x > y) { M2[ai] = y; M2[bi] = x; }
    }
  }
  __syncthreads();
  // round 2: 4 lists -> 2
#pragma unroll
  for (int p = 0; p < 2; ++p) {
    uint64_t a = M2[p * 512 + t], b = M2[p * 512 + 511 - t];
    M[p * 256 + t] = a < b ? a : b;
  }
  for (int str = 128; str > 0; str >>= 1) {
    __syncthreads();
    {
      int q = t;
      int list = q >> 7, r = q & 127;
      int i = ((r & ~(str - 1)) << 1) | (r & (str - 1));
      int ai = list * 256 + i, bi = ai + str;
      uint64_t x = M[ai], y = M[bi];
      if (x > y) { M[ai] = y; M[bi] = x; }
    }
  }
  __syncthreads();
  // round 3: 2 lists -> 1
  {
    uint64_t a = M[t], b = M[511 - t];
    M2[t] = a < b ? a : b;
  }
  for (int str = 128; str > 0; str >>= 1) {
    __syncthreads();
    if (t < 128) {
      int r = t;
      int i = ((r & ~(str - 1)) << 1) | (r & (str - 1));
      uint64_t x = M2[i], y = M2[i + str];
      if (x > y) { M2[i] = y; M2[i + str] = x; }
    }
  }
  __syncthreads();
  idxs[k * KSEL + t] = (int)(unsigned)(M2[t] & 0xFFFFFFFFull);
}

// ---------------- K3a: gather + normalize selected vectors into dense buffers ----------------
// grid ((KSEL+16)/4, NCLS): 4 slots per block -> 4 independent strided loads per thread.
__global__ void k3a_gather(const float* __restrict__ fw, const float* __restrict__ fs,
                           const int* __restrict__ idxw, const int* __restrict__ idxs,
                           const int* __restrict__ wcnt, const int* __restrict__ scnt,
                           float* dw_dense, float* ds_dense) {
  int k = blockIdx.y;
  int s0 = blockIdx.x * 4;
  int t = threadIdx.x;
  int wid = t >> 6, lane = t & 63;
  int kw_ = min(wcnt[k], 16);
  int ks_ = min(scnt[k], KSEL);
  float v[4];
  bool strong[4];
  int slot_[4];
#pragma unroll
  for (int j = 0; j < 4; ++j) {
    int slot = s0 + j;
    slot_[j] = slot;
    strong[j] = slot < KSEL;
    bool ok;
    int n = 0;
    if (strong[j]) {
      ok = slot < ks_;
      if (ok) n = idxs[k * KSEL + slot];
    } else {
      int i = slot - KSEL;
      ok = i < kw_;
      int rank = i > 0 ? i - 1 : 0;  // ranks = max(arange(16)-1, 0)
      if (ok) n = idxw[k * 16 + rank];
    }
    v[j] = 0.0f;
    if (ok) {
      int b = n >> 14, hw = n & (HWSZ - 1);
      const float* f = strong[j] ? fs : fw;
      v[j] = f[(size_t)(b * CDIM + t) * HWSZ + hw];
    }
  }
  __shared__ float wsh[4][4];  // [wave][slot]
  float s[4];
#pragma unroll
  for (int j = 0; j < 4; ++j) {
    s[j] = v[j] * v[j];
    for (int o = 32; o > 0; o >>= 1) s[j] += __shfl_down(s[j], o, 64);
  }
  if (lane == 0) {
#pragma unroll
    for (int j = 0; j < 4; ++j) wsh[wid][j] = s[j];
  }
  __syncthreads();
#pragma unroll
  for (int j = 0; j < 4; ++j) {
    float tot = wsh[0][j] + wsh[1][j] + wsh[2][j] + wsh[3][j];
    float inv = 1.0f / fmaxf(sqrtf(tot), EPSV);
    float out = v[j] * inv;
    if (strong[j]) ds_dense[((size_t)k * KSEL + slot_[j]) * CDIM + t] = out;
    else           dw_dense[((size_t)k * 16 + (slot_[j] - KSEL)) * CDIM + t] = out;
  }
}

// ---------------- K3b: partial cosm row-maxima. grid (4, NCLS) x 64 threads ----------------
__global__ void k3b_loss(const float* __restrict__ dw_dense, const float* __restrict__ ds_dense,
                         const int* __restrict__ scnt, float* pmax) {
  int p = blockIdx.x, k = blockIdx.y, t = threadIdx.x;  // t = 0..63
  __shared__ float wn[16 * CDIM];
  for (int i = t; i < 16 * CDIM; i += 64) wn[i] = dw_dense[(size_t)k * 16 * CDIM + i];
  __syncthreads();
  int ks_ = min(scnt[k], KSEL);
  int slot = p * 64 + t;
  bool jv = slot < ks_;
  float dots[16];
#pragma unroll
  for (int i = 0; i < 16; ++i) dots[i] = 0.0f;
  if (jv) {
    const float4* sp = (const float4*)(ds_dense + ((size_t)k * KSEL + slot) * CDIM);
    for (int c4 = 0; c4 < CDIM / 4; ++c4) {
      float4 v = sp[c4];
#pragma unroll
      for (int i = 0; i < 16; ++i) {
        float4 w = ((const float4*)(wn + i * CDIM))[c4];
        dots[i] = fmaf(v.x, w.x, dots[i]);
        dots[i] = fmaf(v.y, w.y, dots[i]);
        dots[i] = fmaf(v.z, w.z, dots[i]);
        dots[i] = fmaf(v.w, w.w, dots[i]);
      }
    }
  }
#pragma unroll
  for (int i = 0; i < 16; ++i) {
    float v = jv ? dots[i] : NEGV;
    for (int o = 32; o > 0; o >>= 1) v = fmaxf(v, __shfl_down(v, o, 64));
    if (t == 0) pmax[((size_t)k * 4 + p) * 16 + i] = v;
  }
}

// ---------------- K4: memory bank update + loss combine ----------------
__global__ void k4_final(const float* __restrict__ mb, const float* __restrict__ wsum,
                         const int* __restrict__ wcnt, const int* __restrict__ scnt,
                         const float* __restrict__ pmax, float* out) {
  int k = blockIdx.x, t = threadIdx.x;
  float p = mb[k * CDIM + t];
  float o = p;
  int nw = wcnt[k];
  if (nw > 0) {
    float mean = wsum[k * CDIM + t] / (float)nw;
    o = 0.99f * p + 0.01f * mean;
  }
  out[1 + k * CDIM + t] = o;
  if (k == 0) {
    __shared__ float stot;
    __shared__ int ctot;
    if (t == 0) { stot = 0.0f; ctot = 0; }
    __syncthreads();
    float part = 0.0f;
    int cpart = 0;
    for (int idx = t; idx < NCLS * 16; idx += 256) {
      int q = idx >> 4, i = idx & 15;
      int nwq = wcnt[q], nsq = scnt[q];
      if (nwq > 0 && nsq > 0 && i < min(nwq, 16)) {
        float m =    pmax[((size_t)q * 4 + 0) * 16 + i];
        m = fmaxf(m, pmax[((size_t)q * 4 + 1) * 16 + i]);
        m = fmaxf(m, pmax[((size_t)q * 4 + 2) * 16 + i]);
        m = fmaxf(m, pmax[((size_t)q * 4 + 3) * 16 + i]);
        part += m;
      }
    }
    if (t < NCLS) {
      if (wcnt[t] > 0 && scnt[t] > 0) cpart = min(scnt[t], KSEL);
    }
    for (int o2 = 32; o2 > 0; o2 >>= 1) {
      part += __shfl_down(part, o2, 64);
      cpart += __shfl_down(cpart, o2, 64);
    }
    if ((t & 63) == 0) { atomicAdd(&stot, part); atomicAdd(&ctot, cpart); }
    __syncthreads();
    if (t == 0) out[0] = (ctot > 0) ? (1.0f - stot / (float)ctot) : 0.0f;
  }
}

extern "C" void kernel_launch(void* const* d_in, const int* in_sizes, int n_in,
                              void* d_out, int out_size, void* d_ws, size_t ws_size,
                              hipStream_t stream) {
  const float* fw   = (const float*)d_in[0];
  const float* fs   = (const float*)d_in[1];
  const float* prob = (const float*)d_in[2];
  const float* mb   = (const float*)d_in[3];
  const int*   seg  = (const int*)d_in[4];
  const int*   ign  = (const int*)d_in[5];
  float* out = (float*)d_out;

  char* ws = (char*)d_ws;
  size_t off = 0;
  auto alloc = [&](size_t bytes) -> char* {
    char* p = ws + off;
    off = (off + bytes + 255) & ~(size_t)255;
    return p;
  };
  float*    pn       = (float*)alloc(NCLS * CDIM * 4);
  float*    wsum     = (float*)alloc(NCLS * CDIM * 4);
  int*      wcnt     = (int*)alloc(NCLS * 4);
  int*      scnt     = (int*)alloc(NCLS * 4);
  int*      idxw     = (int*)alloc(NCLS * 16 * 4);
  int*      idxs     = (int*)alloc(NCLS * KSEL * 4);
  float*    pmax     = (float*)alloc(NCLS * 4 * 16 * 4);
  uint64_t* wkeys    = (uint64_t*)alloc((size_t)NCLS * CAP_W * 8);
  uint64_t* skeys    = (uint64_t*)alloc((size_t)NCLS * CAP_S * 8);
  uint64_t* psel     = (uint64_t*)alloc((size_t)NCLS * NPART * KSEL * 8);
  float*    dw_dense = (float*)alloc((size_t)NCLS * 16 * CDIM * 4);
  float*    ds_dense = (float*)alloc((size_t)NCLS * KSEL * CDIM * 4);
  (void)in_sizes; (void)n_in; (void)out_size; (void)ws_size;

  k0_init<<<NCLS, 256, 0, stream>>>(mb, pn, wsum, wcnt, scnt);
  k1a_mega<<<NBLKM, 256, 0, stream>>>(fw, fs, prob, seg, ign, pn,
                                      wsum, wcnt, scnt, wkeys, skeys);
  k2_topk<<<NCLS * NPART + NCLS, 256, 0, stream>>>(wkeys, skeys, wcnt, scnt,
                                                   psel, idxw);
  k2m_merge<<<NCLS, 256, 0, stream>>>(psel, idxs);
  k3a_gather<<<dim3((KSEL + 16) / 4, NCLS), 256, 0, stream>>>(fw, fs, idxw, idxs,
                                                              wcnt, scnt,
                                                              dw_dense, ds_dense);
  k3b_loss<<<dim3(4, NCLS), 64, 0, stream>>>(dw_dense, ds_dense, scnt, pmax);
  k4_final<<<NCLS, 256, 0, stream>>>(mb, wsum, wcnt, scnt, pmax, out);
}

// Round 4
// 392.518 us; speedup vs baseline: 1.1315x; 1.1315x over previous
//
#include <hip/hip_runtime.h>
#include <stdint.h>

#define NCLS  21
#define CDIM  256
#define HWSZ  16384
#define NPIX  131072
#define EPSV  1e-6f
#define NEGV  -1e30f
#define CAP_W 4096
#define CAP_S 16384
#define KSEL  256
#define NCC   8            // channel chunks in k1a
#define CCH   (CDIM/NCC)   // 32 channels per chunk
#define NPART 8            // strong top-k partitions per class
#define NBLK2 (NPIX/512)   // 256 pixel groups (512 pixels each) for k1b
#define P2    2048         // pixels per k1a block
#define NPG   (NPIX/P2)    // 64 pixel groups for k1a

__device__ __forceinline__ uint64_t pack_key(float v, unsigned idx) {
  unsigned u = __float_as_uint(v);
  u = (u & 0x80000000u) ? ~u : (u | 0x80000000u);  // order-preserving map
  return ((uint64_t)(~u) << 32) | (uint64_t)idx;   // ascending key == descending value, tie -> low idx
}

// ---------------- K0: normalize prototypes, zero wsum + global counters ----------------
__global__ void k0_init(const float* __restrict__ mb, float* pn, float* wsum,
                        int* wcnt, int* scnt) {
  int k = blockIdx.x, t = threadIdx.x;
  float v = mb[k * CDIM + t];
  float s = v * v;
  for (int o = 32; o > 0; o >>= 1) s += __shfl_down(s, o, 64);
  __shared__ float wsh[4];
  int wid = t >> 6, lane = t & 63;
  if (lane == 0) wsh[wid] = s;
  __syncthreads();
  float tot = wsh[0] + wsh[1] + wsh[2] + wsh[3];
  float inv = 1.0f / fmaxf(sqrtf(tot), EPSV);
  pn[k * CDIM + t] = v * inv;
  wsum[k * CDIM + t] = 0.0f;
  if (k == 0 && t < 2 * NCLS) {
    if (t < NCLS) wcnt[t] = 0; else scnt[t - NCLS] = 0;
  }
}

// ---------------- K1a: streaming pass (Round-2 proven 107us version, unchanged) ----------------
// grid: (NPG=64, NCC=8). Block owns 2048 pixels x 32 channels.
// Thread owns 8 pixels strided by 256 -> every load/store wave-contiguous.
__global__ __launch_bounds__(256, 2)
void k1a_stream(const float* __restrict__ fw, const float* __restrict__ fs,
                const float* __restrict__ prob, const int* __restrict__ seg,
                const int* __restrict__ ign, const float* __restrict__ pn,
                float* part, float* wsum) {
  __shared__ float pnT[CCH * NCLS];          // [c_local][k]
  __shared__ float wloc[NCLS * (CCH + 1)];   // [k][c_local], padded
  int t = threadIdx.x;
  int pg = blockIdx.x;   // 0..63 (2048-pixel group)
  int cc = blockIdx.y;   // 0..7 channel chunk
  int c0 = cc * CCH;
  for (int i = t; i < CCH * NCLS; i += 256) {
    int c = i / NCLS, k = i % NCLS;
    pnT[i] = pn[k * CDIM + c0 + c];
  }
  for (int i = t; i < NCLS * (CCH + 1); i += 256) wloc[i] = 0.0f;
  __syncthreads();

  int base = pg * P2;
  int b = base >> 14;                 // batch (P2 divides HWSZ)
  int hwb = (base & (HWSZ - 1)) + t;  // in-plane offset for this lane

  int sgv[8]; bool cf[8];
  float dw[8], nw[8], dsv[8], nsv[8];
#pragma unroll
  for (int i = 0; i < 8; ++i) {
    int px = base + i * 256 + t;
    sgv[i] = seg[px];
    int igv = ign[px];
    float prv = prob[px];
    cf[i] = (igv != 255) && (prv > 0.95f);
    dw[i] = nw[i] = dsv[i] = nsv[i] = 0.0f;
  }

  const float* fwp = fw + ((size_t)b * CDIM + c0) * HWSZ + hwb;
  const float* fsp = fs + ((size_t)b * CDIM + c0) * HWSZ + hwb;

#pragma unroll 4
  for (int c = 0; c < CCH; ++c) {
    size_t co = (size_t)c * HWSZ;
    float a[8], s8[8];
#pragma unroll
    for (int i = 0; i < 8; ++i) a[i] = fwp[co + i * 256];
#pragma unroll
    for (int i = 0; i < 8; ++i) s8[i] = fsp[co + i * 256];
#pragma unroll
    for (int i = 0; i < 8; ++i) {
      float p = pnT[c * NCLS + sgv[i]];
      dw[i]  = fmaf(a[i],  p,     dw[i]);
      nw[i]  = fmaf(a[i],  a[i],  nw[i]);
      dsv[i] = fmaf(s8[i], p,     dsv[i]);
      nsv[i] = fmaf(s8[i], s8[i], nsv[i]);
      if (cf[i]) atomicAdd(&wloc[sgv[i] * (CCH + 1) + c], a[i]);
    }
  }

  float4* pp = (float4*)part + (size_t)cc * NPIX + base + t;
#pragma unroll
  for (int i = 0; i < 8; ++i)
    pp[i * 256] = make_float4(dw[i], nw[i], dsv[i], nsv[i]);

  __syncthreads();
  for (int i = t; i < NCLS * CCH; i += 256) {
    int k = i / CCH, cl = i % CCH;
    float v = wloc[k * (CCH + 1) + cl];
    if (v != 0.0f) atomicAdd(&wsum[k * CDIM + c0 + cl], v);
  }
}

// ---------------- K1b: combine partials, sims, keys via global atomic range reservation ----------------
// Replaces k1c+ks+old-k1b: per-block LDS counts -> one global atomicAdd per class -> write keys.
// List order nondeterministic; selection deterministic (pack_key embeds pixel index).
__global__ void k1b_write(const float* __restrict__ part, const float* __restrict__ prob,
                          const int* __restrict__ seg, const int* __restrict__ ign,
                          int* wcnt, int* scnt, uint64_t* wkeys, uint64_t* skeys) {
  __shared__ int cs[NCLS], cw[NCLS], bs[NCLS], bw[NCLS];
  int t = threadIdx.x, pg = blockIdx.x;
  for (int i = t; i < NCLS; i += 256) { cs[i] = 0; cw[i] = 0; }
  __syncthreads();
  int n0 = pg * 512 + t * 2;
  int2   sg = *(const int2*)(seg + n0);
  int2   ig = *(const int2*)(ign + n0);
  float2 pr = *(const float2*)(prob + n0);
  float dw[2] = {0,0}, nw[2] = {0,0}, ds[2] = {0,0}, ns[2] = {0,0};
#pragma unroll
  for (int cc = 0; cc < NCC; ++cc) {
    const float4* pp = (const float4*)part + ((size_t)cc * NPIX + n0);
#pragma unroll
    for (int i = 0; i < 2; ++i) {
      float4 v = pp[i];
      dw[i] += v.x; nw[i] += v.y; ds[i] += v.z; ns[i] += v.w;
    }
  }
  int   sga[2] = {sg.x, sg.y};
  int   iga[2] = {ig.x, ig.y};
  float pra[2] = {pr.x, pr.y};
  bool  va[2], cfv[2];
  int   lsl[2] = {0,0}, lwl[2] = {0,0};
#pragma unroll
  for (int i = 0; i < 2; ++i) {
    va[i]  = (iga[i] != 255);
    cfv[i] = va[i] && (pra[i] > 0.95f);
    if (va[i])  lsl[i] = atomicAdd(&cs[sga[i]], 1);
    if (cfv[i]) lwl[i] = atomicAdd(&cw[sga[i]], 1);
  }
  __syncthreads();
  if (t < NCLS) {
    bs[t] = atomicAdd(&scnt[t], cs[t]);
    bw[t] = atomicAdd(&wcnt[t], cw[t]);
  }
  __syncthreads();
#pragma unroll
  for (int i = 0; i < 2; ++i) {
    if (va[i]) {
      int q = sga[i];
      float sim_s = ds[i] / fmaxf(sqrtf(ns[i]), EPSV);
      int pos = bs[q] + lsl[i];
      if (pos < CAP_S) skeys[(size_t)q * CAP_S + pos] = pack_key(-sim_s, (unsigned)(n0 + i));
      if (cfv[i]) {
        float sim_w = dw[i] / fmaxf(sqrtf(nw[i]), EPSV);
        int pw = bw[q] + lwl[i];
        if (pw < CAP_W) wkeys[(size_t)q * CAP_W + pw] = pack_key(sim_w, (unsigned)(n0 + i));
      }
    }
  }
}

// ---------------- top-256 select (cutoff-filtered bitonic), 256 threads ----------------
__device__ void select_topk(const uint64_t* __restrict__ list, int cnt,
                            uint64_t* T, uint64_t* P, int* pcnt, int* woff) {
  int t = threadIdx.x;
  T[t] = ~0ull;
  if (t == 0) *pcnt = 0;
  __syncthreads();
  for (int base = 0; base < cnt; base += 256) {
    uint64_t key = (base + t < cnt) ? list[base + t] : ~0ull;
    uint64_t cutoff = T[KSEL - 1];
    bool pred = key < cutoff;
    unsigned long long mask = __ballot(pred);
    int wid = t >> 6, lane = t & 63;
    if (lane == 0) woff[wid] = __popcll(mask);
    int prefix = __popcll(mask & ((1ull << lane) - 1ull));
    __syncthreads();
    int off = 0;
    for (int w2 = 0; w2 < wid; ++w2) off += woff[w2];
    int total = woff[0] + woff[1] + woff[2] + woff[3];
    int old = *pcnt;
    if (pred) P[old + off + prefix] = key;
    int newc = old + total;
    __syncthreads();
    if (t == 0) *pcnt = newc;
    bool last = (base + 256 >= cnt);
    if (newc >= KSEL || (last && newc > 0)) {
      for (int i2 = t; i2 < 2 * KSEL; i2 += 256)
        if (i2 >= newc) P[i2] = ~0ull;
      for (unsigned size = 2; size <= 2 * KSEL; size <<= 1) {
        for (unsigned stride = size >> 1; stride > 0; stride >>= 1) {
          __syncthreads();
          unsigned lo = stride - 1;
          unsigned i = (((unsigned)t & ~lo) << 1) | ((unsigned)t & lo);
          unsigned j = i | stride;
          uint64_t a = P[i], b = P[j];
          bool up = ((i & size) == 0);
          if ((a > b) == up) { P[i] = b; P[j] = a; }
        }
      }
      __syncthreads();
      uint64_t a = T[t], b = P[KSEL - 1 - t];
      T[t] = a < b ? a : b;
      for (unsigned stride = KSEL / 2; stride > 0; stride >>= 1) {
        __syncthreads();
        if (((unsigned)t & stride) == 0) {
          uint64_t x = T[t], y = T[t + stride];
          if (x > y) { T[t] = y; T[t + stride] = x; }
        }
      }
      __syncthreads();
      if (t == 0) *pcnt = 0;
      __syncthreads();
    } else {
      __syncthreads();
    }
  }
}

// ---------------- K2: weak top-16 (full) + strong top-256 (partitioned) ----------------
__global__ void k2_topk(const uint64_t* __restrict__ wkeys, const uint64_t* __restrict__ skeys,
                        const int* wcnt, const int* scnt,
                        uint64_t* psel, int* idxw) {
  __shared__ uint64_t T[KSEL];
  __shared__ uint64_t P[2 * KSEL];
  __shared__ int pcnt;
  __shared__ int woff[4];
  int bid = blockIdx.x, t = threadIdx.x;
  if (bid < NCLS * NPART) {
    int k = bid / NPART, p = bid % NPART;
    int cnt = min(scnt[k], CAP_S);
    int chunk = (cnt + NPART - 1) / NPART;
    int lo = p * chunk;
    int hi = min(lo + chunk, cnt);
    int c = hi > lo ? hi - lo : 0;
    select_topk(skeys + (size_t)k * CAP_S + lo, c, T, P, &pcnt, woff);
    psel[((size_t)k * NPART + p) * KSEL + t] = T[t];
  } else {
    int k = bid - NCLS * NPART;
    int cnt = min(wcnt[k], CAP_W);
    select_topk(wkeys + (size_t)k * CAP_W, cnt, T, P, &pcnt, woff);
    if (t < 16) idxw[k * 16 + t] = (int)(unsigned)(T[t] & 0xFFFFFFFFull);
  }
}

// ---------------- K2m: merge 8 sorted 256-lists -> top-256 via min-merge + bitonic clean ----------------
__global__ void k2m_merge(const uint64_t* __restrict__ psel, int* idxs) {
  int k = blockIdx.x, t = threadIdx.x;
  __shared__ uint64_t M[NPART * KSEL];   // 2048
  __shared__ uint64_t M2[4 * KSEL];      // 1024
  for (int i = t; i < NPART * KSEL; i += 256) M[i] = psel[(size_t)k * NPART * KSEL + i];
  __syncthreads();
  // round 1: 8 lists -> 4
#pragma unroll
  for (int p = 0; p < 4; ++p) {
    uint64_t a = M[p * 512 + t], b = M[p * 512 + 511 - t];
    M2[p * 256 + t] = a < b ? a : b;
  }
  for (int str = 128; str > 0; str >>= 1) {
    __syncthreads();
    for (int q = t; q < 4 * 128; q += 256) {
      int list = q >> 7, r = q & 127;
      int i = ((r & ~(str - 1)) << 1) | (r & (str - 1));
      int ai = list * 256 + i, bi = ai + str;
      uint64_t x = M2[ai], y = M2[bi];
      if (x > y) { M2[ai] = y; M2[bi] = x; }
    }
  }
  __syncthreads();
  // round 2: 4 lists -> 2
#pragma unroll
  for (int p = 0; p < 2; ++p) {
    uint64_t a = M2[p * 512 + t], b = M2[p * 512 + 511 - t];
    M[p * 256 + t] = a < b ? a : b;
  }
  for (int str = 128; str > 0; str >>= 1) {
    __syncthreads();
    {
      int q = t;
      int list = q >> 7, r = q & 127;
      int i = ((r & ~(str - 1)) << 1) | (r & (str - 1));
      int ai = list * 256 + i, bi = ai + str;
      uint64_t x = M[ai], y = M[bi];
      if (x > y) { M[ai] = y; M[bi] = x; }
    }
  }
  __syncthreads();
  // round 3: 2 lists -> 1
  {
    uint64_t a = M[t], b = M[511 - t];
    M2[t] = a < b ? a : b;
  }
  for (int str = 128; str > 0; str >>= 1) {
    __syncthreads();
    if (t < 128) {
      int r = t;
      int i = ((r & ~(str - 1)) << 1) | (r & (str - 1));
      uint64_t x = M2[i], y = M2[i + str];
      if (x > y) { M2[i] = y; M2[i + str] = x; }
    }
  }
  __syncthreads();
  idxs[k * KSEL + t] = (int)(unsigned)(M2[t] & 0xFFFFFFFFull);
}

// ---------------- K3a: gather + normalize selected vectors into dense buffers ----------------
// grid ((KSEL+16)/4, NCLS): 4 slots per block -> 4 independent strided loads per thread.
__global__ void k3a_gather(const float* __restrict__ fw, const float* __restrict__ fs,
                           const int* __restrict__ idxw, const int* __restrict__ idxs,
                           const int* __restrict__ wcnt, const int* __restrict__ scnt,
                           float* dw_dense, float* ds_dense) {
  int k = blockIdx.y;
  int s0 = blockIdx.x * 4;
  int t = threadIdx.x;
  int wid = t >> 6, lane = t & 63;
  int kw_ = min(wcnt[k], 16);
  int ks_ = min(scnt[k], KSEL);
  float v[4];
  bool strong[4];
  int slot_[4];
#pragma unroll
  for (int j = 0; j < 4; ++j) {
    int slot = s0 + j;
    slot_[j] = slot;
    strong[j] = slot < KSEL;
    bool ok;
    int n = 0;
    if (strong[j]) {
      ok = slot < ks_;
      if (ok) n = idxs[k * KSEL + slot];
    } else {
      int i = slot - KSEL;
      ok = i < kw_;
      int rank = i > 0 ? i - 1 : 0;  // ranks = max(arange(16)-1, 0)
      if (ok) n = idxw[k * 16 + rank];
    }
    v[j] = 0.0f;
    if (ok) {
      int b = n >> 14, hw = n & (HWSZ - 1);
      const float* f = strong[j] ? fs : fw;
      v[j] = f[(size_t)(b * CDIM + t) * HWSZ + hw];
    }
  }
  __shared__ float wsh[4][4];  // [wave][slot]
  float s[4];
#pragma unroll
  for (int j = 0; j < 4; ++j) {
    s[j] = v[j] * v[j];
    for (int o = 32; o > 0; o >>= 1) s[j] += __shfl_down(s[j], o, 64);
  }
  if (lane == 0) {
#pragma unroll
    for (int j = 0; j < 4; ++j) wsh[wid][j] = s[j];
  }
  __syncthreads();
#pragma unroll
  for (int j = 0; j < 4; ++j) {
    float tot = wsh[0][j] + wsh[1][j] + wsh[2][j] + wsh[3][j];
    float inv = 1.0f / fmaxf(sqrtf(tot), EPSV);
    float out = v[j] * inv;
    if (strong[j]) ds_dense[((size_t)k * KSEL + slot_[j]) * CDIM + t] = out;
    else           dw_dense[((size_t)k * 16 + (slot_[j] - KSEL)) * CDIM + t] = out;
  }
}

// ---------------- K3b: partial cosm row-maxima. grid (4, NCLS) x 64 threads ----------------
__global__ void k3b_loss(const float* __restrict__ dw_dense, const float* __restrict__ ds_dense,
                         const int* __restrict__ scnt, float* pmax) {
  int p = blockIdx.x, k = blockIdx.y, t = threadIdx.x;  // t = 0..63
  __shared__ float wn[16 * CDIM];
  for (int i = t; i < 16 * CDIM; i += 64) wn[i] = dw_dense[(size_t)k * 16 * CDIM + i];
  __syncthreads();
  int ks_ = min(scnt[k], KSEL);
  int slot = p * 64 + t;
  bool jv = slot < ks_;
  float dots[16];
#pragma unroll
  for (int i = 0; i < 16; ++i) dots[i] = 0.0f;
  if (jv) {
    const float4* sp = (const float4*)(ds_dense + ((size_t)k * KSEL + slot) * CDIM);
    for (int c4 = 0; c4 < CDIM / 4; ++c4) {
      float4 v = sp[c4];
#pragma unroll
      for (int i = 0; i < 16; ++i) {
        float4 w = ((const float4*)(wn + i * CDIM))[c4];
        dots[i] = fmaf(v.x, w.x, dots[i]);
        dots[i] = fmaf(v.y, w.y, dots[i]);
        dots[i] = fmaf(v.z, w.z, dots[i]);
        dots[i] = fmaf(v.w, w.w, dots[i]);
      }
    }
  }
#pragma unroll
  for (int i = 0; i < 16; ++i) {
    float v = jv ? dots[i] : NEGV;
    for (int o = 32; o > 0; o >>= 1) v = fmaxf(v, __shfl_down(v, o, 64));
    if (t == 0) pmax[((size_t)k * 4 + p) * 16 + i] = v;
  }
}

// ---------------- K4: memory bank update + loss combine ----------------
__global__ void k4_final(const float* __restrict__ mb, const float* __restrict__ wsum,
                         const int* __restrict__ wcnt, const int* __restrict__ scnt,
                         const float* __restrict__ pmax, float* out) {
  int k = blockIdx.x, t = threadIdx.x;
  float p = mb[k * CDIM + t];
  float o = p;
  int nw = wcnt[k];
  if (nw > 0) {
    float mean = wsum[k * CDIM + t] / (float)nw;
    o = 0.99f * p + 0.01f * mean;
  }
  out[1 + k * CDIM + t] = o;
  if (k == 0) {
    __shared__ float stot;
    __shared__ int ctot;
    if (t == 0) { stot = 0.0f; ctot = 0; }
    __syncthreads();
    float part = 0.0f;
    int cpart = 0;
    for (int idx = t; idx < NCLS * 16; idx += 256) {
      int q = idx >> 4, i = idx & 15;
      int nwq = wcnt[q], nsq = scnt[q];
      if (nwq > 0 && nsq > 0 && i < min(nwq, 16)) {
        float m =    pmax[((size_t)q * 4 + 0) * 16 + i];
        m = fmaxf(m, pmax[((size_t)q * 4 + 1) * 16 + i]);
        m = fmaxf(m, pmax[((size_t)q * 4 + 2) * 16 + i]);
        m = fmaxf(m, pmax[((size_t)q * 4 + 3) * 16 + i]);
        part += m;
      }
    }
    if (t < NCLS) {
      if (wcnt[t] > 0 && scnt[t] > 0) cpart = min(scnt[t], KSEL);
    }
    for (int o2 = 32; o2 > 0; o2 >>= 1) {
      part += __shfl_down(part, o2, 64);
      cpart += __shfl_down(cpart, o2, 64);
    }
    if ((t & 63) == 0) { atomicAdd(&stot, part); atomicAdd(&ctot, cpart); }
    __syncthreads();
    if (t == 0) out[0] = (ctot > 0) ? (1.0f - stot / (float)ctot) : 0.0f;
  }
}

extern "C" void kernel_launch(void* const* d_in, const int* in_sizes, int n_in,
                              void* d_out, int out_size, void* d_ws, size_t ws_size,
                              hipStream_t stream) {
  const float* fw   = (const float*)d_in[0];
  const float* fs   = (const float*)d_in[1];
  const float* prob = (const float*)d_in[2];
  const float* mb   = (const float*)d_in[3];
  const int*   seg  = (const int*)d_in[4];
  const int*   ign  = (const int*)d_in[5];
  float* out = (float*)d_out;

  char* ws = (char*)d_ws;
  size_t off = 0;
  auto alloc = [&](size_t bytes) -> char* {
    char* p = ws + off;
    off = (off + bytes + 255) & ~(size_t)255;
    return p;
  };
  float*    pn       = (float*)alloc(NCLS * CDIM * 4);
  float*    wsum     = (float*)alloc(NCLS * CDIM * 4);
  int*      wcnt     = (int*)alloc(NCLS * 4);
  int*      scnt     = (int*)alloc(NCLS * 4);
  int*      idxw     = (int*)alloc(NCLS * 16 * 4);
  int*      idxs     = (int*)alloc(NCLS * KSEL * 4);
  float*    pmax     = (float*)alloc(NCLS * 4 * 16 * 4);
  uint64_t* wkeys    = (uint64_t*)alloc((size_t)NCLS * CAP_W * 8);
  uint64_t* skeys    = (uint64_t*)alloc((size_t)NCLS * CAP_S * 8);
  uint64_t* psel     = (uint64_t*)alloc((size_t)NCLS * NPART * KSEL * 8);
  float*    dw_dense = (float*)alloc((size_t)NCLS * 16 * CDIM * 4);
  float*    ds_dense = (float*)alloc((size_t)NCLS * KSEL * CDIM * 4);
  float*    part     = (float*)alloc((size_t)NCC * NPIX * 4 * 4);  // 16.8 MB
  (void)in_sizes; (void)n_in; (void)out_size; (void)ws_size;

  k0_init<<<NCLS, 256, 0, stream>>>(mb, pn, wsum, wcnt, scnt);
  k1a_stream<<<dim3(NPG, NCC), 256, 0, stream>>>(fw, fs, prob, seg, ign, pn,
                                                 part, wsum);
  k1b_write<<<NBLK2, 256, 0, stream>>>(part, prob, seg, ign, wcnt, scnt,
                                       wkeys, skeys);
  k2_topk<<<NCLS * NPART + NCLS, 256, 0, stream>>>(wkeys, skeys, wcnt, scnt,
                                                   psel, idxw);
  k2m_merge<<<NCLS, 256, 0, stream>>>(psel, idxs);
  k3a_gather<<<dim3((KSEL + 16) / 4, NCLS), 256, 0, stream>>>(fw, fs, idxw, idxs,
                                                              wcnt, scnt,
                                                              dw_dense, ds_dense);
  k3b_loss<<<dim3(4, NCLS), 64, 0, stream>>>(dw_dense, ds_dense, scnt, pmax);
  k4_final<<<NCLS, 256, 0, stream>>>(mb, wsum, wcnt, scnt, pmax, out);
}

// Round 5
// 382.487 us; speedup vs baseline: 1.1612x; 1.0262x over previous
//
#include <hip/hip_runtime.h>
#include <stdint.h>

#define NCLS  21
#define CDIM  256
#define HWSZ  16384
#define NPIX  131072
#define EPSV  1e-6f
#define NEGV  -1e30f
#define CAP_W 4096
#define CAP_S 16384
#define KSEL  256
#define NCC   8            // channel chunks in k1a
#define CCH   (CDIM/NCC)   // 32 channels per chunk
#define NPART 8            // strong top-k partitions per class
#define NBLK2 (NPIX/512)   // 256 pixel groups (512 pixels each) for k1b
#define P2    2048         // pixels per k1a block
#define NPG   (NPIX/P2)    // 64 pixel groups for k1a

__device__ __forceinline__ uint64_t pack_key(float v, unsigned idx) {
  unsigned u = __float_as_uint(v);
  u = (u & 0x80000000u) ? ~u : (u | 0x80000000u);  // order-preserving map
  return ((uint64_t)(~u) << 32) | (uint64_t)idx;   // ascending key == descending value, tie -> low idx
}

// ---------------- K0: normalize prototypes, zero wsum + global counters ----------------
__global__ void k0_init(const float* __restrict__ mb, float* pn, float* wsum,
                        int* wcnt, int* scnt) {
  int k = blockIdx.x, t = threadIdx.x;
  float v = mb[k * CDIM + t];
  float s = v * v;
  for (int o = 32; o > 0; o >>= 1) s += __shfl_down(s, o, 64);
  __shared__ float wsh[4];
  int wid = t >> 6, lane = t & 63;
  if (lane == 0) wsh[wid] = s;
  __syncthreads();
  float tot = wsh[0] + wsh[1] + wsh[2] + wsh[3];
  float inv = 1.0f / fmaxf(sqrtf(tot), EPSV);
  pn[k * CDIM + t] = v * inv;
  wsum[k * CDIM + t] = 0.0f;
  if (k == 0 && t < 2 * NCLS) {
    if (t < NCLS) wcnt[t] = 0; else scnt[t - NCLS] = 0;
  }
}

// ---------------- K1a: streaming pass (proven 107us version, unchanged) ----------------
__global__ __launch_bounds__(256, 2)
void k1a_stream(const float* __restrict__ fw, const float* __restrict__ fs,
                const float* __restrict__ prob, const int* __restrict__ seg,
                const int* __restrict__ ign, const float* __restrict__ pn,
                float* part, float* wsum) {
  __shared__ float pnT[CCH * NCLS];          // [c_local][k]
  __shared__ float wloc[NCLS * (CCH + 1)];   // [k][c_local], padded
  int t = threadIdx.x;
  int pg = blockIdx.x;   // 0..63 (2048-pixel group)
  int cc = blockIdx.y;   // 0..7 channel chunk
  int c0 = cc * CCH;
  for (int i = t; i < CCH * NCLS; i += 256) {
    int c = i / NCLS, k = i % NCLS;
    pnT[i] = pn[k * CDIM + c0 + c];
  }
  for (int i = t; i < NCLS * (CCH + 1); i += 256) wloc[i] = 0.0f;
  __syncthreads();

  int base = pg * P2;
  int b = base >> 14;                 // batch (P2 divides HWSZ)
  int hwb = (base & (HWSZ - 1)) + t;  // in-plane offset for this lane

  int sgv[8]; bool cf[8];
  float dw[8], nw[8], dsv[8], nsv[8];
#pragma unroll
  for (int i = 0; i < 8; ++i) {
    int px = base + i * 256 + t;
    sgv[i] = seg[px];
    int igv = ign[px];
    float prv = prob[px];
    cf[i] = (igv != 255) && (prv > 0.95f);
    dw[i] = nw[i] = dsv[i] = nsv[i] = 0.0f;
  }

  const float* fwp = fw + ((size_t)b * CDIM + c0) * HWSZ + hwb;
  const float* fsp = fs + ((size_t)b * CDIM + c0) * HWSZ + hwb;

#pragma unroll 4
  for (int c = 0; c < CCH; ++c) {
    size_t co = (size_t)c * HWSZ;
    float a[8], s8[8];
#pragma unroll
    for (int i = 0; i < 8; ++i) a[i] = fwp[co + i * 256];
#pragma unroll
    for (int i = 0; i < 8; ++i) s8[i] = fsp[co + i * 256];
#pragma unroll
    for (int i = 0; i < 8; ++i) {
      float p = pnT[c * NCLS + sgv[i]];
      dw[i]  = fmaf(a[i],  p,     dw[i]);
      nw[i]  = fmaf(a[i],  a[i],  nw[i]);
      dsv[i] = fmaf(s8[i], p,     dsv[i]);
      nsv[i] = fmaf(s8[i], s8[i], nsv[i]);
      if (cf[i]) atomicAdd(&wloc[sgv[i] * (CCH + 1) + c], a[i]);
    }
  }

  float4* pp = (float4*)part + (size_t)cc * NPIX + base + t;
#pragma unroll
  for (int i = 0; i < 8; ++i)
    pp[i * 256] = make_float4(dw[i], nw[i], dsv[i], nsv[i]);

  __syncthreads();
  for (int i = t; i < NCLS * CCH; i += 256) {
    int k = i / CCH, cl = i % CCH;
    float v = wloc[k * (CCH + 1) + cl];
    if (v != 0.0f) atomicAdd(&wsum[k * CDIM + c0 + cl], v);
  }
}

// ---------------- K1b: combine partials, sims, keys + reciprocal norms ----------------
__global__ void k1b_write(const float* __restrict__ part, const float* __restrict__ prob,
                          const int* __restrict__ seg, const int* __restrict__ ign,
                          int* wcnt, int* scnt, uint64_t* wkeys, uint64_t* skeys,
                          float* rnorm_w, float* rnorm_s) {
  __shared__ int cs[NCLS], cw[NCLS], bs[NCLS], bw[NCLS];
  int t = threadIdx.x, pg = blockIdx.x;
  for (int i = t; i < NCLS; i += 256) { cs[i] = 0; cw[i] = 0; }
  __syncthreads();
  int n0 = pg * 512 + t * 2;
  int2   sg = *(const int2*)(seg + n0);
  int2   ig = *(const int2*)(ign + n0);
  float2 pr = *(const float2*)(prob + n0);
  float dw[2] = {0,0}, nw[2] = {0,0}, ds[2] = {0,0}, ns[2] = {0,0};
#pragma unroll
  for (int cc = 0; cc < NCC; ++cc) {
    const float4* pp = (const float4*)part + ((size_t)cc * NPIX + n0);
#pragma unroll
    for (int i = 0; i < 2; ++i) {
      float4 v = pp[i];
      dw[i] += v.x; nw[i] += v.y; ds[i] += v.z; ns[i] += v.w;
    }
  }
  // reciprocal norms for downstream vector normalization (all pixels, coalesced)
  float2 rw = { 1.0f / fmaxf(sqrtf(nw[0]), EPSV), 1.0f / fmaxf(sqrtf(nw[1]), EPSV) };
  float2 rs = { 1.0f / fmaxf(sqrtf(ns[0]), EPSV), 1.0f / fmaxf(sqrtf(ns[1]), EPSV) };
  *(float2*)(rnorm_w + n0) = rw;
  *(float2*)(rnorm_s + n0) = rs;

  int   sga[2] = {sg.x, sg.y};
  int   iga[2] = {ig.x, ig.y};
  float pra[2] = {pr.x, pr.y};
  bool  va[2], cfv[2];
  int   lsl[2] = {0,0}, lwl[2] = {0,0};
#pragma unroll
  for (int i = 0; i < 2; ++i) {
    va[i]  = (iga[i] != 255);
    cfv[i] = va[i] && (pra[i] > 0.95f);
    if (va[i])  lsl[i] = atomicAdd(&cs[sga[i]], 1);
    if (cfv[i]) lwl[i] = atomicAdd(&cw[sga[i]], 1);
  }
  __syncthreads();
  if (t < NCLS) {
    bs[t] = atomicAdd(&scnt[t], cs[t]);
    bw[t] = atomicAdd(&wcnt[t], cw[t]);
  }
  __syncthreads();
#pragma unroll
  for (int i = 0; i < 2; ++i) {
    if (va[i]) {
      int q = sga[i];
      float sim_s = ds[i] / fmaxf(sqrtf(ns[i]), EPSV);
      int pos = bs[q] + lsl[i];
      if (pos < CAP_S) skeys[(size_t)q * CAP_S + pos] = pack_key(-sim_s, (unsigned)(n0 + i));
      if (cfv[i]) {
        float sim_w = dw[i] / fmaxf(sqrtf(nw[i]), EPSV);
        int pw = bw[q] + lwl[i];
        if (pw < CAP_W) wkeys[(size_t)q * CAP_W + pw] = pack_key(sim_w, (unsigned)(n0 + i));
      }
    }
  }
}

// ---------------- top-256 select (cutoff-filtered bitonic), 256 threads ----------------
__device__ void select_topk(const uint64_t* __restrict__ list, int cnt,
                            uint64_t* T, uint64_t* P, int* pcnt, int* woff) {
  int t = threadIdx.x;
  T[t] = ~0ull;
  if (t == 0) *pcnt = 0;
  __syncthreads();
  for (int base = 0; base < cnt; base += 256) {
    uint64_t key = (base + t < cnt) ? list[base + t] : ~0ull;
    uint64_t cutoff = T[KSEL - 1];
    bool pred = key < cutoff;
    unsigned long long mask = __ballot(pred);
    int wid = t >> 6, lane = t & 63;
    if (lane == 0) woff[wid] = __popcll(mask);
    int prefix = __popcll(mask & ((1ull << lane) - 1ull));
    __syncthreads();
    int off = 0;
    for (int w2 = 0; w2 < wid; ++w2) off += woff[w2];
    int total = woff[0] + woff[1] + woff[2] + woff[3];
    int old = *pcnt;
    if (pred) P[old + off + prefix] = key;
    int newc = old + total;
    __syncthreads();
    if (t == 0) *pcnt = newc;
    bool last = (base + 256 >= cnt);
    if (newc >= KSEL || (last && newc > 0)) {
      for (int i2 = t; i2 < 2 * KSEL; i2 += 256)
        if (i2 >= newc) P[i2] = ~0ull;
      for (unsigned size = 2; size <= 2 * KSEL; size <<= 1) {
        for (unsigned stride = size >> 1; stride > 0; stride >>= 1) {
          __syncthreads();
          unsigned lo = stride - 1;
          unsigned i = (((unsigned)t & ~lo) << 1) | ((unsigned)t & lo);
          unsigned j = i | stride;
          uint64_t a = P[i], b = P[j];
          bool up = ((i & size) == 0);
          if ((a > b) == up) { P[i] = b; P[j] = a; }
        }
      }
      __syncthreads();
      uint64_t a = T[t], b = P[KSEL - 1 - t];
      T[t] = a < b ? a : b;
      for (unsigned stride = KSEL / 2; stride > 0; stride >>= 1) {
        __syncthreads();
        if (((unsigned)t & stride) == 0) {
          uint64_t x = T[t], y = T[t + stride];
          if (x > y) { T[t] = y; T[t + stride] = x; }
        }
      }
      __syncthreads();
      if (t == 0) *pcnt = 0;
      __syncthreads();
    } else {
      __syncthreads();
    }
  }
}

// ---------------- K2: weak top-16 (full) + strong top-256 (partitioned) ----------------
__global__ void k2_topk(const uint64_t* __restrict__ wkeys, const uint64_t* __restrict__ skeys,
                        const int* wcnt, const int* scnt,
                        uint64_t* psel, int* idxw) {
  __shared__ uint64_t T[KSEL];
  __shared__ uint64_t P[2 * KSEL];
  __shared__ int pcnt;
  __shared__ int woff[4];
  int bid = blockIdx.x, t = threadIdx.x;
  if (bid < NCLS * NPART) {
    int k = bid / NPART, p = bid % NPART;
    int cnt = min(scnt[k], CAP_S);
    int chunk = (cnt + NPART - 1) / NPART;
    int lo = p * chunk;
    int hi = min(lo + chunk, cnt);
    int c = hi > lo ? hi - lo : 0;
    select_topk(skeys + (size_t)k * CAP_S + lo, c, T, P, &pcnt, woff);
    psel[((size_t)k * NPART + p) * KSEL + t] = T[t];
  } else {
    int k = bid - NCLS * NPART;
    int cnt = min(wcnt[k], CAP_W);
    select_topk(wkeys + (size_t)k * CAP_W, cnt, T, P, &pcnt, woff);
    if (t < 16) idxw[k * 16 + t] = (int)(unsigned)(T[t] & 0xFFFFFFFFull);
  }
}

// ---------------- K2m: merge partitions -> idxs; gather+normalize weak -> dw_dense ----------------
__global__ void k2m_merge(const uint64_t* __restrict__ psel, const int* __restrict__ wcnt,
                          const int* __restrict__ idxw, const float* __restrict__ fw,
                          const float* __restrict__ rnorm_w,
                          int* idxs, float* dw_dense) {
  int k = blockIdx.x, t = threadIdx.x;
  // --- weak gather (independent of merge; issued first to hide latency) ---
  int kw_ = min(wcnt[k], 16);
  float wv[16];
#pragma unroll
  for (int i = 0; i < 16; ++i) {
    wv[i] = 0.0f;
    if (i < kw_) {
      int ri = i > 0 ? i - 1 : 0;   // ranks = max(arange(16)-1, 0)
      int n = idxw[k * 16 + ri];
      int b = n >> 14, hw = n & (HWSZ - 1);
      float v = fw[((size_t)b * CDIM + t) * HWSZ + hw];
      wv[i] = v * rnorm_w[n];
    }
  }
  // --- strong merge: 8 sorted 256-lists -> top-256 (min-merge + bitonic clean) ---
  __shared__ uint64_t M[NPART * KSEL];   // 2048
  __shared__ uint64_t M2[4 * KSEL];      // 1024
  for (int i = t; i < NPART * KSEL; i += 256) M[i] = psel[(size_t)k * NPART * KSEL + i];
  __syncthreads();
#pragma unroll
  for (int p = 0; p < 4; ++p) {
    uint64_t a = M[p * 512 + t], b = M[p * 512 + 511 - t];
    M2[p * 256 + t] = a < b ? a : b;
  }
  for (int str = 128; str > 0; str >>= 1) {
    __syncthreads();
    for (int q = t; q < 4 * 128; q += 256) {
      int list = q >> 7, r = q & 127;
      int i = ((r & ~(str - 1)) << 1) | (r & (str - 1));
      int ai = list * 256 + i, bi = ai + str;
      uint64_t x = M2[ai], y = M2[bi];
      if (x > y) { M2[ai] = y; M2[bi] = x; }
    }
  }
  __syncthreads();
#pragma unroll
  for (int p = 0; p < 2; ++p) {
    uint64_t a = M2[p * 512 + t], b = M2[p * 512 + 511 - t];
    M[p * 256 + t] = a < b ? a : b;
  }
  for (int str = 128; str > 0; str >>= 1) {
    __syncthreads();
    {
      int q = t;
      int list = q >> 7, r = q & 127;
      int i = ((r & ~(str - 1)) << 1) | (r & (str - 1));
      int ai = list * 256 + i, bi = ai + str;
      uint64_t x = M[ai], y = M[bi];
      if (x > y) { M[ai] = y; M[bi] = x; }
    }
  }
  __syncthreads();
  {
    uint64_t a = M[t], b = M[511 - t];
    M2[t] = a < b ? a : b;
  }
  for (int str = 128; str > 0; str >>= 1) {
    __syncthreads();
    if (t < 128) {
      int r = t;
      int i = ((r & ~(str - 1)) << 1) | (r & (str - 1));
      uint64_t x = M2[i], y = M2[i + str];
      if (x > y) { M2[i] = y; M2[i + str] = x; }
    }
  }
  __syncthreads();
  idxs[k * KSEL + t] = (int)(unsigned)(M2[t] & 0xFFFFFFFFull);
  // --- store normalized weak matrix ---
#pragma unroll
  for (int i = 0; i < 16; ++i)
    dw_dense[((size_t)k * 16 + i) * CDIM + t] = wv[i];
}

// ---------------- K3f: fused strong gather + dots + row-maxima ----------------
// grid (4, NCLS), 256 threads. Block p owns strong slots [p*64, p*64+64).
// thread t: slot j = t&63, channel segment cseg = t>>6 (64 channels).
__global__ void k3f_loss(const float* __restrict__ fs, const float* __restrict__ dw_dense,
                         const int* __restrict__ idxs, const float* __restrict__ rnorm_s,
                         const int* __restrict__ scnt, float* pmax) {
  int p = blockIdx.x, k = blockIdx.y, t = threadIdx.x;
  __shared__ float wnS[16 * CDIM];       // normalized weak, [i][c]
  __shared__ float pd[4][64][16];        // [cseg][j][i]
  for (int i = t; i < 16 * CDIM; i += 256) wnS[i] = dw_dense[(size_t)k * 16 * CDIM + i];

  int ks_ = min(scnt[k], KSEL);
  int j = t & 63, cseg = t >> 6;
  int slot = p * 64 + j;
  bool jv = slot < ks_;
  int n = 0;
  float rn = 0.0f;
  if (jv) {
    n = idxs[k * KSEL + slot];
    rn = rnorm_s[n];
  }
  int b = n >> 14, hw = n & (HWSZ - 1);
  const float* sp = fs + ((size_t)b * CDIM + cseg * 64) * HWSZ + hw;

  float acc[16];
#pragma unroll
  for (int i = 0; i < 16; ++i) acc[i] = 0.0f;
  __syncthreads();

  if (jv) {
#pragma unroll 4
    for (int c4 = 0; c4 < 16; ++c4) {
      float v0 = sp[(size_t)(4 * c4 + 0) * HWSZ];
      float v1 = sp[(size_t)(4 * c4 + 1) * HWSZ];
      float v2 = sp[(size_t)(4 * c4 + 2) * HWSZ];
      float v3 = sp[(size_t)(4 * c4 + 3) * HWSZ];
#pragma unroll
      for (int i = 0; i < 16; ++i) {
        float4 w = ((const float4*)(wnS + i * CDIM + cseg * 64))[c4];
        acc[i] = fmaf(v0, w.x, acc[i]);
        acc[i] = fmaf(v1, w.y, acc[i]);
        acc[i] = fmaf(v2, w.z, acc[i]);
        acc[i] = fmaf(v3, w.w, acc[i]);
      }
    }
  }
#pragma unroll
  for (int i = 0; i < 16; ++i) pd[cseg][j][i] = acc[i];
  __syncthreads();

  // reduce: wave w handles i in [4w, 4w+4); lane = slot j
  int lane = t & 63, w = t >> 6;
  float mv[4];
#pragma unroll
  for (int q = 0; q < 4; ++q) {
    int i = w * 4 + q;
    float d = pd[0][lane][i] + pd[1][lane][i] + pd[2][lane][i] + pd[3][lane][i];
    d *= rn;                    // rn corresponds to this thread's lane (= j)
    mv[q] = jv ? d : NEGV;
    for (int o = 32; o > 0; o >>= 1) mv[q] = fmaxf(mv[q], __shfl_down(mv[q], o, 64));
  }
  if (lane == 0) {
#pragma unroll
    for (int q = 0; q < 4; ++q)
      pmax[((size_t)k * 4 + p) * 16 + w * 4 + q] = mv[q];
  }
}

// ---------------- K4: memory bank update + loss combine ----------------
__global__ void k4_final(const float* __restrict__ mb, const float* __restrict__ wsum,
                         const int* __restrict__ wcnt, const int* __restrict__ scnt,
                         const float* __restrict__ pmax, float* out) {
  int k = blockIdx.x, t = threadIdx.x;
  float p = mb[k * CDIM + t];
  float o = p;
  int nw = wcnt[k];
  if (nw > 0) {
    float mean = wsum[k * CDIM + t] / (float)nw;
    o = 0.99f * p + 0.01f * mean;
  }
  out[1 + k * CDIM + t] = o;
  if (k == 0) {
    __shared__ float stot;
    __shared__ int ctot;
    if (t == 0) { stot = 0.0f; ctot = 0; }
    __syncthreads();
    float part = 0.0f;
    int cpart = 0;
    for (int idx = t; idx < NCLS * 16; idx += 256) {
      int q = idx >> 4, i = idx & 15;
      int nwq = wcnt[q], nsq = scnt[q];
      if (nwq > 0 && nsq > 0 && i < min(nwq, 16)) {
        float m =    pmax[((size_t)q * 4 + 0) * 16 + i];
        m = fmaxf(m, pmax[((size_t)q * 4 + 1) * 16 + i]);
        m = fmaxf(m, pmax[((size_t)q * 4 + 2) * 16 + i]);
        m = fmaxf(m, pmax[((size_t)q * 4 + 3) * 16 + i]);
        part += m;
      }
    }
    if (t < NCLS) {
      if (wcnt[t] > 0 && scnt[t] > 0) cpart = min(scnt[t], KSEL);
    }
    for (int o2 = 32; o2 > 0; o2 >>= 1) {
      part += __shfl_down(part, o2, 64);
      cpart += __shfl_down(cpart, o2, 64);
    }
    if ((t & 63) == 0) { atomicAdd(&stot, part); atomicAdd(&ctot, cpart); }
    __syncthreads();
    if (t == 0) out[0] = (ctot > 0) ? (1.0f - stot / (float)ctot) : 0.0f;
  }
}

extern "C" void kernel_launch(void* const* d_in, const int* in_sizes, int n_in,
                              void* d_out, int out_size, void* d_ws, size_t ws_size,
                              hipStream_t stream) {
  const float* fw   = (const float*)d_in[0];
  const float* fs   = (const float*)d_in[1];
  const float* prob = (const float*)d_in[2];
  const float* mb   = (const float*)d_in[3];
  const int*   seg  = (const int*)d_in[4];
  const int*   ign  = (const int*)d_in[5];
  float* out = (float*)d_out;

  char* ws = (char*)d_ws;
  size_t off = 0;
  auto alloc = [&](size_t bytes) -> char* {
    char* p = ws + off;
    off = (off + bytes + 255) & ~(size_t)255;
    return p;
  };
  float*    pn       = (float*)alloc(NCLS * CDIM * 4);
  float*    wsum     = (float*)alloc(NCLS * CDIM * 4);
  int*      wcnt     = (int*)alloc(NCLS * 4);
  int*      scnt     = (int*)alloc(NCLS * 4);
  int*      idxw     = (int*)alloc(NCLS * 16 * 4);
  int*      idxs     = (int*)alloc(NCLS * KSEL * 4);
  float*    pmax     = (float*)alloc(NCLS * 4 * 16 * 4);
  float*    rnorm_w  = (float*)alloc((size_t)NPIX * 4);
  float*    rnorm_s  = (float*)alloc((size_t)NPIX * 4);
  uint64_t* wkeys    = (uint64_t*)alloc((size_t)NCLS * CAP_W * 8);
  uint64_t* skeys    = (uint64_t*)alloc((size_t)NCLS * CAP_S * 8);
  uint64_t* psel     = (uint64_t*)alloc((size_t)NCLS * NPART * KSEL * 8);
  float*    dw_dense = (float*)alloc((size_t)NCLS * 16 * CDIM * 4);
  float*    part     = (float*)alloc((size_t)NCC * NPIX * 4 * 4);  // 16.8 MB
  (void)in_sizes; (void)n_in; (void)out_size; (void)ws_size;

  k0_init<<<NCLS, 256, 0, stream>>>(mb, pn, wsum, wcnt, scnt);
  k1a_stream<<<dim3(NPG, NCC), 256, 0, stream>>>(fw, fs, prob, seg, ign, pn,
                                                 part, wsum);
  k1b_write<<<NBLK2, 256, 0, stream>>>(part, prob, seg, ign, wcnt, scnt,
                                       wkeys, skeys, rnorm_w, rnorm_s);
  k2_topk<<<NCLS * NPART + NCLS, 256, 0, stream>>>(wkeys, skeys, wcnt, scnt,
                                                   psel, idxw);
  k2m_merge<<<NCLS, 256, 0, stream>>>(psel, wcnt, idxw, fw, rnorm_w,
                                      idxs, dw_dense);
  k3f_loss<<<dim3(4, NCLS), 256, 0, stream>>>(fs, dw_dense, idxs, rnorm_s,
                                              scnt, pmax);
  k4_final<<<NCLS, 256, 0, stream>>>(mb, wsum, wcnt, scnt, pmax, out);
}

// Round 6
// 374.250 us; speedup vs baseline: 1.1868x; 1.0220x over previous
//
#include <hip/hip_runtime.h>
#include <stdint.h>

#define NCLS  21
#define CDIM  256
#define HWSZ  16384
#define NPIX  131072
#define EPSV  1e-6f
#define NEGV  -1e30f
#define CAP_W 4096
#define CAP_S 16384
#define KSEL  256
#define NCC   8            // channel chunks in k1a
#define CCH   (CDIM/NCC)   // 32 channels per chunk
#define NPART 8            // strong top-k partitions per class
#define NBLK2 (NPIX/512)   // 256 pixel groups (512 pixels each) for k1b
#define P2    2048         // pixels per k1a block
#define NPG   (NPIX/P2)    // 64 pixel groups for k1a
#define SPART 16           // k3f strong-slot partitions per class

__device__ __forceinline__ uint64_t pack_key(float v, unsigned idx) {
  unsigned u = __float_as_uint(v);
  u = (u & 0x80000000u) ? ~u : (u | 0x80000000u);  // order-preserving map
  return ((uint64_t)(~u) << 32) | (uint64_t)idx;   // ascending key == descending value, tie -> low idx
}

// ---------------- K0: normalize prototypes, zero wsum + global counters ----------------
__global__ void k0_init(const float* __restrict__ mb, float* pn, float* wsum,
                        int* wcnt, int* scnt) {
  int k = blockIdx.x, t = threadIdx.x;
  float v = mb[k * CDIM + t];
  float s = v * v;
  for (int o = 32; o > 0; o >>= 1) s += __shfl_down(s, o, 64);
  __shared__ float wsh[4];
  int wid = t >> 6, lane = t & 63;
  if (lane == 0) wsh[wid] = s;
  __syncthreads();
  float tot = wsh[0] + wsh[1] + wsh[2] + wsh[3];
  float inv = 1.0f / fmaxf(sqrtf(tot), EPSV);
  pn[k * CDIM + t] = v * inv;
  wsum[k * CDIM + t] = 0.0f;
  if (k == 0 && t < 2 * NCLS) {
    if (t < NCLS) wcnt[t] = 0; else scnt[t - NCLS] = 0;
  }
}

// ---------------- K1a: streaming pass (proven 107us version, unchanged) ----------------
__global__ __launch_bounds__(256, 2)
void k1a_stream(const float* __restrict__ fw, const float* __restrict__ fs,
                const float* __restrict__ prob, const int* __restrict__ seg,
                const int* __restrict__ ign, const float* __restrict__ pn,
                float* part, float* wsum) {
  __shared__ float pnT[CCH * NCLS];          // [c_local][k]
  __shared__ float wloc[NCLS * (CCH + 1)];   // [k][c_local], padded
  int t = threadIdx.x;
  int pg = blockIdx.x;   // 0..63 (2048-pixel group)
  int cc = blockIdx.y;   // 0..7 channel chunk
  int c0 = cc * CCH;
  for (int i = t; i < CCH * NCLS; i += 256) {
    int c = i / NCLS, k = i % NCLS;
    pnT[i] = pn[k * CDIM + c0 + c];
  }
  for (int i = t; i < NCLS * (CCH + 1); i += 256) wloc[i] = 0.0f;
  __syncthreads();

  int base = pg * P2;
  int b = base >> 14;                 // batch (P2 divides HWSZ)
  int hwb = (base & (HWSZ - 1)) + t;  // in-plane offset for this lane

  int sgv[8]; bool cf[8];
  float dw[8], nw[8], dsv[8], nsv[8];
#pragma unroll
  for (int i = 0; i < 8; ++i) {
    int px = base + i * 256 + t;
    sgv[i] = seg[px];
    int igv = ign[px];
    float prv = prob[px];
    cf[i] = (igv != 255) && (prv > 0.95f);
    dw[i] = nw[i] = dsv[i] = nsv[i] = 0.0f;
  }

  const float* fwp = fw + ((size_t)b * CDIM + c0) * HWSZ + hwb;
  const float* fsp = fs + ((size_t)b * CDIM + c0) * HWSZ + hwb;

#pragma unroll 4
  for (int c = 0; c < CCH; ++c) {
    size_t co = (size_t)c * HWSZ;
    float a[8], s8[8];
#pragma unroll
    for (int i = 0; i < 8; ++i) a[i] = fwp[co + i * 256];
#pragma unroll
    for (int i = 0; i < 8; ++i) s8[i] = fsp[co + i * 256];
#pragma unroll
    for (int i = 0; i < 8; ++i) {
      float p = pnT[c * NCLS + sgv[i]];
      dw[i]  = fmaf(a[i],  p,     dw[i]);
      nw[i]  = fmaf(a[i],  a[i],  nw[i]);
      dsv[i] = fmaf(s8[i], p,     dsv[i]);
      nsv[i] = fmaf(s8[i], s8[i], nsv[i]);
      if (cf[i]) atomicAdd(&wloc[sgv[i] * (CCH + 1) + c], a[i]);
    }
  }

  float4* pp = (float4*)part + (size_t)cc * NPIX + base + t;
#pragma unroll
  for (int i = 0; i < 8; ++i)
    pp[i * 256] = make_float4(dw[i], nw[i], dsv[i], nsv[i]);

  __syncthreads();
  for (int i = t; i < NCLS * CCH; i += 256) {
    int k = i / CCH, cl = i % CCH;
    float v = wloc[k * (CCH + 1) + cl];
    if (v != 0.0f) atomicAdd(&wsum[k * CDIM + c0 + cl], v);
  }
}

// ---------------- K1b: combine partials, sims, keys + reciprocal norms ----------------
__global__ void k1b_write(const float* __restrict__ part, const float* __restrict__ prob,
                          const int* __restrict__ seg, const int* __restrict__ ign,
                          int* wcnt, int* scnt, uint64_t* wkeys, uint64_t* skeys,
                          float* rnorm_w, float* rnorm_s) {
  __shared__ int cs[NCLS], cw[NCLS], bs[NCLS], bw[NCLS];
  int t = threadIdx.x, pg = blockIdx.x;
  for (int i = t; i < NCLS; i += 256) { cs[i] = 0; cw[i] = 0; }
  __syncthreads();
  int n0 = pg * 512 + t * 2;
  int2   sg = *(const int2*)(seg + n0);
  int2   ig = *(const int2*)(ign + n0);
  float2 pr = *(const float2*)(prob + n0);
  float dw[2] = {0,0}, nw[2] = {0,0}, ds[2] = {0,0}, ns[2] = {0,0};
#pragma unroll
  for (int cc = 0; cc < NCC; ++cc) {
    const float4* pp = (const float4*)part + ((size_t)cc * NPIX + n0);
#pragma unroll
    for (int i = 0; i < 2; ++i) {
      float4 v = pp[i];
      dw[i] += v.x; nw[i] += v.y; ds[i] += v.z; ns[i] += v.w;
    }
  }
  // reciprocal norms for downstream vector normalization (all pixels, coalesced)
  float2 rw = { 1.0f / fmaxf(sqrtf(nw[0]), EPSV), 1.0f / fmaxf(sqrtf(nw[1]), EPSV) };
  float2 rs = { 1.0f / fmaxf(sqrtf(ns[0]), EPSV), 1.0f / fmaxf(sqrtf(ns[1]), EPSV) };
  *(float2*)(rnorm_w + n0) = rw;
  *(float2*)(rnorm_s + n0) = rs;

  int   sga[2] = {sg.x, sg.y};
  int   iga[2] = {ig.x, ig.y};
  float pra[2] = {pr.x, pr.y};
  bool  va[2], cfv[2];
  int   lsl[2] = {0,0}, lwl[2] = {0,0};
#pragma unroll
  for (int i = 0; i < 2; ++i) {
    va[i]  = (iga[i] != 255);
    cfv[i] = va[i] && (pra[i] > 0.95f);
    if (va[i])  lsl[i] = atomicAdd(&cs[sga[i]], 1);
    if (cfv[i]) lwl[i] = atomicAdd(&cw[sga[i]], 1);
  }
  __syncthreads();
  if (t < NCLS) {
    bs[t] = atomicAdd(&scnt[t], cs[t]);
    bw[t] = atomicAdd(&wcnt[t], cw[t]);
  }
  __syncthreads();
#pragma unroll
  for (int i = 0; i < 2; ++i) {
    if (va[i]) {
      int q = sga[i];
      float sim_s = ds[i] / fmaxf(sqrtf(ns[i]), EPSV);
      int pos = bs[q] + lsl[i];
      if (pos < CAP_S) skeys[(size_t)q * CAP_S + pos] = pack_key(-sim_s, (unsigned)(n0 + i));
      if (cfv[i]) {
        float sim_w = dw[i] / fmaxf(sqrtf(nw[i]), EPSV);
        int pw = bw[q] + lwl[i];
        if (pw < CAP_W) wkeys[(size_t)q * CAP_W + pw] = pack_key(sim_w, (unsigned)(n0 + i));
      }
    }
  }
}

// ---------------- top-256 select (cutoff-filtered bitonic), 256 threads ----------------
__device__ void select_topk(const uint64_t* __restrict__ list, int cnt,
                            uint64_t* T, uint64_t* P, int* pcnt, int* woff) {
  int t = threadIdx.x;
  T[t] = ~0ull;
  if (t == 0) *pcnt = 0;
  __syncthreads();
  for (int base = 0; base < cnt; base += 256) {
    uint64_t key = (base + t < cnt) ? list[base + t] : ~0ull;
    uint64_t cutoff = T[KSEL - 1];
    bool pred = key < cutoff;
    unsigned long long mask = __ballot(pred);
    int wid = t >> 6, lane = t & 63;
    if (lane == 0) woff[wid] = __popcll(mask);
    int prefix = __popcll(mask & ((1ull << lane) - 1ull));
    __syncthreads();
    int off = 0;
    for (int w2 = 0; w2 < wid; ++w2) off += woff[w2];
    int total = woff[0] + woff[1] + woff[2] + woff[3];
    int old = *pcnt;
    if (pred) P[old + off + prefix] = key;
    int newc = old + total;
    __syncthreads();
    if (t == 0) *pcnt = newc;
    bool last = (base + 256 >= cnt);
    if (newc >= KSEL || (last && newc > 0)) {
      for (int i2 = t; i2 < 2 * KSEL; i2 += 256)
        if (i2 >= newc) P[i2] = ~0ull;
      for (unsigned size = 2; size <= 2 * KSEL; size <<= 1) {
        for (unsigned stride = size >> 1; stride > 0; stride >>= 1) {
          __syncthreads();
          unsigned lo = stride - 1;
          unsigned i = (((unsigned)t & ~lo) << 1) | ((unsigned)t & lo);
          unsigned j = i | stride;
          uint64_t a = P[i], b = P[j];
          bool up = ((i & size) == 0);
          if ((a > b) == up) { P[i] = b; P[j] = a; }
        }
      }
      __syncthreads();
      uint64_t a = T[t], b = P[KSEL - 1 - t];
      T[t] = a < b ? a : b;
      for (unsigned stride = KSEL / 2; stride > 0; stride >>= 1) {
        __syncthreads();
        if (((unsigned)t & stride) == 0) {
          uint64_t x = T[t], y = T[t + stride];
          if (x > y) { T[t] = y; T[t + stride] = x; }
        }
      }
      __syncthreads();
      if (t == 0) *pcnt = 0;
      __syncthreads();
    } else {
      __syncthreads();
    }
  }
}

// ---------------- K2: weak top-16 (full) + strong top-256 (partitioned) ----------------
__global__ void k2_topk(const uint64_t* __restrict__ wkeys, const uint64_t* __restrict__ skeys,
                        const int* wcnt, const int* scnt,
                        uint64_t* psel, int* idxw) {
  __shared__ uint64_t T[KSEL];
  __shared__ uint64_t P[2 * KSEL];
  __shared__ int pcnt;
  __shared__ int woff[4];
  int bid = blockIdx.x, t = threadIdx.x;
  if (bid < NCLS * NPART) {
    int k = bid / NPART, p = bid % NPART;
    int cnt = min(scnt[k], CAP_S);
    int chunk = (cnt + NPART - 1) / NPART;
    int lo = p * chunk;
    int hi = min(lo + chunk, cnt);
    int c = hi > lo ? hi - lo : 0;
    select_topk(skeys + (size_t)k * CAP_S + lo, c, T, P, &pcnt, woff);
    psel[((size_t)k * NPART + p) * KSEL + t] = T[t];
  } else {
    int k = bid - NCLS * NPART;
    int cnt = min(wcnt[k], CAP_W);
    select_topk(wkeys + (size_t)k * CAP_W, cnt, T, P, &pcnt, woff);
    if (t < 16) idxw[k * 16 + t] = (int)(unsigned)(T[t] & 0xFFFFFFFFull);
  }
}

// ---------------- K2m: merge partitions -> idxs; gather+normalize weak -> dw_dense ----------------
__global__ void k2m_merge(const uint64_t* __restrict__ psel, const int* __restrict__ wcnt,
                          const int* __restrict__ idxw, const float* __restrict__ fw,
                          const float* __restrict__ rnorm_w,
                          int* idxs, float* dw_dense) {
  int k = blockIdx.x, t = threadIdx.x;
  // --- weak gather (independent of merge; issued first to hide latency) ---
  int kw_ = min(wcnt[k], 16);
  float wv[16];
#pragma unroll
  for (int i = 0; i < 16; ++i) {
    wv[i] = 0.0f;
    if (i < kw_) {
      int ri = i > 0 ? i - 1 : 0;   // ranks = max(arange(16)-1, 0)
      int n = idxw[k * 16 + ri];
      int b = n >> 14, hw = n & (HWSZ - 1);
      float v = fw[((size_t)b * CDIM + t) * HWSZ + hw];
      wv[i] = v * rnorm_w[n];
    }
  }
  // --- strong merge: 8 sorted 256-lists -> top-256 (min-merge + bitonic clean) ---
  __shared__ uint64_t M[NPART * KSEL];   // 2048
  __shared__ uint64_t M2[4 * KSEL];      // 1024
  for (int i = t; i < NPART * KSEL; i += 256) M[i] = psel[(size_t)k * NPART * KSEL + i];
  __syncthreads();
#pragma unroll
  for (int p = 0; p < 4; ++p) {
    uint64_t a = M[p * 512 + t], b = M[p * 512 + 511 - t];
    M2[p * 256 + t] = a < b ? a : b;
  }
  for (int str = 128; str > 0; str >>= 1) {
    __syncthreads();
    for (int q = t; q < 4 * 128; q += 256) {
      int list = q >> 7, r = q & 127;
      int i = ((r & ~(str - 1)) << 1) | (r & (str - 1));
      int ai = list * 256 + i, bi = ai + str;
      uint64_t x = M2[ai], y = M2[bi];
      if (x > y) { M2[ai] = y; M2[bi] = x; }
    }
  }
  __syncthreads();
#pragma unroll
  for (int p = 0; p < 2; ++p) {
    uint64_t a = M2[p * 512 + t], b = M2[p * 512 + 511 - t];
    M[p * 256 + t] = a < b ? a : b;
  }
  for (int str = 128; str > 0; str >>= 1) {
    __syncthreads();
    {
      int q = t;
      int list = q >> 7, r = q & 127;
      int i = ((r & ~(str - 1)) << 1) | (r & (str - 1));
      int ai = list * 256 + i, bi = ai + str;
      uint64_t x = M[ai], y = M[bi];
      if (x > y) { M[ai] = y; M[bi] = x; }
    }
  }
  __syncthreads();
  {
    uint64_t a = M[t], b = M[511 - t];
    M2[t] = a < b ? a : b;
  }
  for (int str = 128; str > 0; str >>= 1) {
    __syncthreads();
    if (t < 128) {
      int r = t;
      int i = ((r & ~(str - 1)) << 1) | (r & (str - 1));
      uint64_t x = M2[i], y = M2[i + str];
      if (x > y) { M2[i] = y; M2[i + str] = x; }
    }
  }
  __syncthreads();
  idxs[k * KSEL + t] = (int)(unsigned)(M2[t] & 0xFFFFFFFFull);
  // --- store normalized weak matrix ---
#pragma unroll
  for (int i = 0; i < 16; ++i)
    dw_dense[((size_t)k * 16 + i) * CDIM + t] = wv[i];
}

// ---------------- K3f: fused strong gather + dots + row-maxima ----------------
// grid (SPART=16, NCLS) = 336 blocks. Block p owns strong slots [p*16, p*16+16).
// thread t: slot j = t&15, channel segment cseg = t>>4 (16 channels each).
// 16 independent scattered loads per thread; 1344 waves total (vs 336 before).
__global__ void k3f_loss(const float* __restrict__ fs, const float* __restrict__ dw_dense,
                         const int* __restrict__ idxs, const float* __restrict__ rnorm_s,
                         const int* __restrict__ scnt, float* pmax) {
  int p = blockIdx.x, k = blockIdx.y, t = threadIdx.x;
  __shared__ float wnS[16 * CDIM];       // normalized weak, [i][c]  16 KB
  __shared__ float pd[16][16][17];       // [cseg][j][i] padded      17.4 KB
  for (int i = t; i < 16 * CDIM; i += 256) wnS[i] = dw_dense[(size_t)k * 16 * CDIM + i];

  int ks_ = min(scnt[k], KSEL);
  int j = t & 15, cseg = t >> 4;
  int slot = p * 16 + j;
  bool jv = slot < ks_;
  int n = 0;
  float rn = 0.0f;
  if (jv) {
    n = idxs[k * KSEL + slot];
    rn = rnorm_s[n];
  }
  int b = n >> 14, hw = n & (HWSZ - 1);
  const float* sp = fs + ((size_t)b * CDIM + cseg * 16) * HWSZ + hw;

  float acc[16];
#pragma unroll
  for (int i = 0; i < 16; ++i) acc[i] = 0.0f;
  __syncthreads();   // wnS ready

  if (jv) {
#pragma unroll
    for (int c4 = 0; c4 < 4; ++c4) {
      float v0 = sp[(size_t)(4 * c4 + 0) * HWSZ];
      float v1 = sp[(size_t)(4 * c4 + 1) * HWSZ];
      float v2 = sp[(size_t)(4 * c4 + 2) * HWSZ];
      float v3 = sp[(size_t)(4 * c4 + 3) * HWSZ];
#pragma unroll
      for (int i = 0; i < 16; ++i) {
        float4 w = *(const float4*)(wnS + i * CDIM + cseg * 16 + c4 * 4);
        acc[i] = fmaf(v0, w.x, acc[i]);
        acc[i] = fmaf(v1, w.y, acc[i]);
        acc[i] = fmaf(v2, w.z, acc[i]);
        acc[i] = fmaf(v3, w.w, acc[i]);
      }
    }
  }
  // fold per-slot rnorm in before the cseg reduction (rn identical across cseg of a slot)
#pragma unroll
  for (int i = 0; i < 16; ++i) pd[cseg][j][i] = acc[i] * rn;
  __syncthreads();

  // reduction: thread t -> (i2 = t>>4, j2 = t&15); sum over cseg, max over j2
  int i2 = t >> 4, j2 = t & 15;
  bool v2 = (p * 16 + j2) < ks_;
  float d = 0.0f;
#pragma unroll
  for (int cs2 = 0; cs2 < 16; ++cs2) d += pd[cs2][j2][i2];
  d = v2 ? d : NEGV;
  for (int o = 8; o > 0; o >>= 1) d = fmaxf(d, __shfl_xor(d, o, 64));
  if (j2 == 0) pmax[((size_t)k * SPART + p) * 16 + i2] = d;
}

// ---------------- K4: memory bank update + loss combine ----------------
__global__ void k4_final(const float* __restrict__ mb, const float* __restrict__ wsum,
                         const int* __restrict__ wcnt, const int* __restrict__ scnt,
                         const float* __restrict__ pmax, float* out) {
  int k = blockIdx.x, t = threadIdx.x;
  float p = mb[k * CDIM + t];
  float o = p;
  int nw = wcnt[k];
  if (nw > 0) {
    float mean = wsum[k * CDIM + t] / (float)nw;
    o = 0.99f * p + 0.01f * mean;
  }
  out[1 + k * CDIM + t] = o;
  if (k == 0) {
    __shared__ float stot;
    __shared__ int ctot;
    if (t == 0) { stot = 0.0f; ctot = 0; }
    __syncthreads();
    float part = 0.0f;
    int cpart = 0;
    for (int idx = t; idx < NCLS * 16; idx += 256) {
      int q = idx >> 4, i = idx & 15;
      int nwq = wcnt[q], nsq = scnt[q];
      if (nwq > 0 && nsq > 0 && i < min(nwq, 16)) {
        float m = NEGV;
#pragma unroll
        for (int pp = 0; pp < SPART; ++pp)
          m = fmaxf(m, pmax[((size_t)q * SPART + pp) * 16 + i]);
        part += m;
      }
    }
    if (t < NCLS) {
      if (wcnt[t] > 0 && scnt[t] > 0) cpart = min(scnt[t], KSEL);
    }
    for (int o2 = 32; o2 > 0; o2 >>= 1) {
      part += __shfl_down(part, o2, 64);
      cpart += __shfl_down(cpart, o2, 64);
    }
    if ((t & 63) == 0) { atomicAdd(&stot, part); atomicAdd(&ctot, cpart); }
    __syncthreads();
    if (t == 0) out[0] = (ctot > 0) ? (1.0f - stot / (float)ctot) : 0.0f;
  }
}

extern "C" void kernel_launch(void* const* d_in, const int* in_sizes, int n_in,
                              void* d_out, int out_size, void* d_ws, size_t ws_size,
                              hipStream_t stream) {
  const float* fw   = (const float*)d_in[0];
  const float* fs   = (const float*)d_in[1];
  const float* prob = (const float*)d_in[2];
  const float* mb   = (const float*)d_in[3];
  const int*   seg  = (const int*)d_in[4];
  const int*   ign  = (const int*)d_in[5];
  float* out = (float*)d_out;

  char* ws = (char*)d_ws;
  size_t off = 0;
  auto alloc = [&](size_t bytes) -> char* {
    char* p = ws + off;
    off = (off + bytes + 255) & ~(size_t)255;
    return p;
  };
  float*    pn       = (float*)alloc(NCLS * CDIM * 4);
  float*    wsum     = (float*)alloc(NCLS * CDIM * 4);
  int*      wcnt     = (int*)alloc(NCLS * 4);
  int*      scnt     = (int*)alloc(NCLS * 4);
  int*      idxw     = (int*)alloc(NCLS * 16 * 4);
  int*      idxs     = (int*)alloc(NCLS * KSEL * 4);
  float*    pmax     = (float*)alloc((size_t)NCLS * SPART * 16 * 4);
  float*    rnorm_w  = (float*)alloc((size_t)NPIX * 4);
  float*    rnorm_s  = (float*)alloc((size_t)NPIX * 4);
  uint64_t* wkeys    = (uint64_t*)alloc((size_t)NCLS * CAP_W * 8);
  uint64_t* skeys    = (uint64_t*)alloc((size_t)NCLS * CAP_S * 8);
  uint64_t* psel     = (uint64_t*)alloc((size_t)NCLS * NPART * KSEL * 8);
  float*    dw_dense = (float*)alloc((size_t)NCLS * 16 * CDIM * 4);
  float*    part     = (float*)alloc((size_t)NCC * NPIX * 4 * 4);  // 16.8 MB
  (void)in_sizes; (void)n_in; (void)out_size; (void)ws_size;

  k0_init<<<NCLS, 256, 0, stream>>>(mb, pn, wsum, wcnt, scnt);
  k1a_stream<<<dim3(NPG, NCC), 256, 0, stream>>>(fw, fs, prob, seg, ign, pn,
                                                 part, wsum);
  k1b_write<<<NBLK2, 256, 0, stream>>>(part, prob, seg, ign, wcnt, scnt,
                                       wkeys, skeys, rnorm_w, rnorm_s);
  k2_topk<<<NCLS * NPART + NCLS, 256, 0, stream>>>(wkeys, skeys, wcnt, scnt,
                                                   psel, idxw);
  k2m_merge<<<NCLS, 256, 0, stream>>>(psel, wcnt, idxw, fw, rnorm_w,
                                      idxs, dw_dense);
  k3f_loss<<<dim3(SPART, NCLS), 256, 0, stream>>>(fs, dw_dense, idxs, rnorm_s,
                                                  scnt, pmax);
  k4_final<<<NCLS, 256, 0, stream>>>(mb, wsum, wcnt, scnt, pmax, out);
}